// Round 6
// baseline (314.322 us; speedup 1.0000x reference)
//
#include <hip/hip_runtime.h>
#include <math.h>

#define BATCH 131072
#define DIM 256
#define NK 5
#define BT 3.0f
#define NBLK 1024    // 4 blocks/CU x 256 CU, exactly co-resident
#define NTHR 512     // 8 waves/block -> 32 waves/CU
#define ITERS 8      // BATCH / (NBLK * 8 waves * 2 rows)

typedef float f32x4 __attribute__((ext_vector_type(4)));   // native clang vector:
// __builtin_nontemporal_store requires scalar/clang-vector types (HIP float4 is a class).

__global__ __launch_bounds__(NTHR, 8) void rqs_kernel(
    const float* __restrict__ u,
    const float* __restrict__ wp,
    const float* __restrict__ hp,
    const float* __restrict__ dp,
    float* __restrict__ x_out,
    float* __restrict__ ld_out)
{
    // Lane l owns dims 4l..4l+3  ->  u load / x store are ONE float4 (dwordx4) per row.
    // (round 0-2 used scalar 4 B/lane global I/O: 4x the VMEM instructions.)
    //
    // Tables are PERMUTED so the gather stays conflict-free under this mapping:
    //   record for dim d lives at slot perm(d) = (d&3)*64 + (d>>2) within each k-plane.
    //   Gather for (lane l, sub-dim c): slot = c*64 + l -> 64 contiguous float4s per
    //   (c, idx) -> 16 B/lane stride ds_read_b128, the canonical conflict-free pattern.
    //   tabA[k*DIM+perm(d)] = (xk, 1/width, s = dk+dk1-2*delta, delta)
    //   tabB[k*DIM+perm(d)] = (p = h*(delta-dk), q = h*dk, yk, rb = 2*(delta-dk))
    // Math:  theta = (uc-xk)*iw
    //        denom = fma(fma(-s,th,s),th,delta)            (= delta + s*th*(1-th))
    //        num   = th*fma(p,th,q)                        (= h*(delta*th^2 + dk*th(1-th)))
    //        ldq   = fma(fma(s,th,rb),th,dk)               (= dk1*th^2+2delta*th(1-th)+dk*(1-th)^2)
    //        ld    = log(ldq * delta^2 * invd^2)
    // At th==0 (low tail, dk=1) and th==1 (high tail, dk1=1) the log argument is 1 -> ld==0,
    // so no 'inside' select needed on ld.
    //
    // Cross-iteration u prefetch RESTORED: the valid same-node A/B (round 1 vs round 2)
    // showed it is a +14% win (127 vs 145 us) and even lowers FETCH. The round-1
    // "regression" vs round 0 was environmental (different node), not the prefetch.
    __shared__ float4 tabA[NK * DIM];   // 20480 B
    __shared__ float4 tabB[NK * DIM];   // 20480 B ; total 40960 -> 4 blocks = 160 KiB/CU
    const int tid = threadIdx.x;

    if (tid < DIM) {
        const int dm = tid;
        float v[NK], wid[NK], xpos[NK], hei[NK], ypos[NK], dv[NK + 1];
        float mx, sum, scale, c;

        mx = -1e30f;
        #pragma unroll
        for (int k = 0; k < NK; k++) { v[k] = wp[dm * NK + k]; mx = fmaxf(mx, v[k]); }
        sum = 0.f;
        #pragma unroll
        for (int k = 0; k < NK; k++) { v[k] = expf(v[k] - mx); sum += v[k]; }
        scale = 6.0f / sum;
        c = -BT;
        #pragma unroll
        for (int k = 0; k < NK; k++) { wid[k] = v[k] * scale; xpos[k] = c; c += wid[k]; }

        mx = -1e30f;
        #pragma unroll
        for (int k = 0; k < NK; k++) { v[k] = hp[dm * NK + k]; mx = fmaxf(mx, v[k]); }
        sum = 0.f;
        #pragma unroll
        for (int k = 0; k < NK; k++) { v[k] = expf(v[k] - mx); sum += v[k]; }
        scale = 6.0f / sum;
        c = -BT;
        #pragma unroll
        for (int k = 0; k < NK; k++) { hei[k] = v[k] * scale; ypos[k] = c; c += hei[k]; }

        dv[0] = 1.0f; dv[NK] = 1.0f;
        #pragma unroll
        for (int k = 0; k < 4; k++) dv[1 + k] = log1pf(expf(dp[dm * 4 + k]));

        const int s_ = ((dm & 3) << 6) | (dm >> 2);   // permuted slot
        #pragma unroll
        for (int k = 0; k < NK; k++) {
            float iw  = 1.0f / wid[k];
            float dlt = hei[k] * iw;
            float dk  = dv[k], dk1 = dv[k + 1];
            tabA[k * DIM + s_] = make_float4(xpos[k], iw, dk + dk1 - 2.0f * dlt, dlt);
            tabB[k * DIM + s_] = make_float4(hei[k] * (dlt - dk), hei[k] * dk,
                                             ypos[k], 2.0f * (dlt - dk));
        }
    }
    __syncthreads();

    const int lane = tid & 63;
    const int wv   = tid >> 6;

    // interior x-knots for this lane's 4 dims: kn[c][i] = left edge of bin i+1 of dim 4*lane+c
    float kn[4][4];
    #pragma unroll
    for (int c = 0; c < 4; c++)
        #pragma unroll
        for (int i = 0; i < 4; i++)
            kn[c][i] = tabA[(i + 1) * DIM + (c << 6) + lane].x;

    const int g = (blockIdx.x << 3) | wv;   // global wave id, 0..8191

    // prefetch of iteration 0's u rows (one float4 per row)
    f32x4 uin[2];
    {
        const float* up = u + ((size_t)(g << 1)) * DIM + (lane << 2);
        uin[0] = *(const f32x4*)up;
        uin[1] = *(const f32x4*)(up + DIM);
    }

    for (int it = 0; it < ITERS; it++) {
        const int r0 = (it << 14) | (g << 1);   // 16384 contiguous rows per sweep

        // prefetch NEXT iteration's u: issued a full iteration ahead of use
        f32x4 unx[2];
        if (it + 1 < ITERS) {
            const float* up = u + ((size_t)(r0 + 16384)) * DIM + (lane << 2);
            unx[0] = *(const f32x4*)up;
            unx[1] = *(const f32x4*)(up + DIM);
        }

        float ldacc0 = 0.f, ldacc1 = 0.f;

        #pragma unroll
        for (int rr = 0; rr < 2; rr++) {
            f32x4 xv;
            float lsum = 0.f;
            #pragma unroll
            for (int c = 0; c < 4; c++) {
                float uval = uin[rr][c];
                float uc = fminf(fmaxf(uval, -BT), BT);
                int idx = (int)(uc >= kn[c][0]) + (int)(uc >= kn[c][1])
                        + (int)(uc >= kn[c][2]) + (int)(uc >= kn[c][3]);
                const int off = (idx << 8) + (c << 6) + lane;
                float4 A  = tabA[off];
                float4 Bv = tabB[off];
                float xk = A.x,  iw = A.y,  s  = A.z,  dlt = A.w;
                float p  = Bv.x, q  = Bv.y, yk = Bv.z, rb  = Bv.w;

                float th    = (uc - xk) * iw;
                float dk    = fmaf(-0.5f, rb, dlt);
                float r2    = dlt * dlt;
                float denom = fmaf(fmaf(-s, th, s), th, dlt);
                float invd  = __builtin_amdgcn_rcpf(denom);
                float num   = th * fmaf(p, th, q);
                float x_in  = fmaf(num, invd, yk);
                float ldq   = fmaf(fmaf(s, th, rb), th, dk);
                float ld    = __logf(ldq * r2 * invd * invd);

                xv[c] = (uc == uval) ? x_in : uval;
                lsum += ld;          // == 0 (to fp eps) for tail elements
            }
            if (rr == 0) ldacc0 = lsum; else ldacc1 = lsum;

            __builtin_nontemporal_store(
                xv, (f32x4*)(x_out + (size_t)(r0 + rr) * DIM + (lane << 2)));
        }

        #pragma unroll
        for (int sh = 32; sh > 0; sh >>= 1) {
            ldacc0 += __shfl_down(ldacc0, sh, 64);
            ldacc1 += __shfl_down(ldacc1, sh, 64);
        }
        if (lane == 0) {
            __builtin_nontemporal_store(ldacc0, ld_out + r0);
            __builtin_nontemporal_store(ldacc1, ld_out + r0 + 1);
        }

        if (it + 1 < ITERS) {
            uin[0] = unx[0];
            uin[1] = unx[1];
        }
    }
}

extern "C" void kernel_launch(void* const* d_in, const int* in_sizes, int n_in,
                              void* d_out, int out_size, void* d_ws, size_t ws_size,
                              hipStream_t stream) {
    const float* u  = (const float*)d_in[0];
    const float* w  = (const float*)d_in[1];
    const float* h  = (const float*)d_in[2];
    const float* dd = (const float*)d_in[3];
    float* x  = (float*)d_out;
    float* ld = x + (size_t)BATCH * DIM;
    rqs_kernel<<<NBLK, NTHR, 0, stream>>>(u, w, h, dd, x, ld);
}

// Round 7
// 245.787 us; speedup vs baseline: 1.2788x; 1.2788x over previous
//
#include <hip/hip_runtime.h>
#include <math.h>

#define BATCH 131072
#define DIM 256
#define NK 5
#define BT 3.0f
#define NBLK 1024    // 4 blocks/CU x 256 CU, exactly co-resident
#define NTHR 512     // 8 waves/block -> 32 waves/CU
#define ITERS 8      // BATCH / (NBLK * 8 waves * 2 rows)

__global__ __launch_bounds__(NTHR, 8) void rqs_kernel(
    const float* __restrict__ u,
    const float* __restrict__ wp,
    const float* __restrict__ hp,
    const float* __restrict__ dp,
    float* __restrict__ x_out,
    float* __restrict__ ld_out)
{
    // EXACT round-0 structure (best measured: 100 us/dispatch, FETCH 65.6 MB) with ONE
    // change: the per-(bin,dim) record is split into two arrays (16 B/lane gather stride)
    // instead of interleaved float4 pairs (32 B/lane stride). Verified on the identical
    // gather structure: conflicts 6.36M -> 0.79M cycles (rounds 1/2).
    //   tabA[k*DIM+dim] = (xk, 1/width, s = dk+dk1-2*delta, delta)
    //   tabB[k*DIM+dim] = (p = h*(delta-dk), q = h*dk, yk, rb = 2*(delta-dk))
    // Math:  theta = (uc-xk)*iw
    //        denom = fma(fma(-s,th,s),th,delta)            (= delta + s*th*(1-th))
    //        num   = th*fma(p,th,q)                        (= h*(delta*th^2 + dk*th(1-th)))
    //        ldq   = fma(fma(s,th,rb),th,dk)               (= dk1*th^2+2delta*th(1-th)+dk*(1-th)^2)
    //        ld    = log(ldq * delta^2 * invd^2)
    // At th==0 (low tail, dk=1) and th==1 (high tail, dk1=1) the log argument is 1 -> ld==0,
    // so no 'inside' select needed on ld.
    //
    // REVERTED (same-node A/B r0 vs r6: 100 -> 163 us): float4 lane-remap I/O, permuted
    // table, cross-iteration prefetch. That combo blew up HBM traffic (FETCH 65.6->314 MB,
    // WRITE 132.5->251.5 MB) by widening the live streaming window past L3 residency,
    // and the permuted gather DOUBLED bank conflicts (0.79M->1.77M). Round-0's tight
    // load->compute->store schedule is what keeps u L3-resident across dispatches.
    __shared__ float4 tabA[NK * DIM];   // 20480 B
    __shared__ float4 tabB[NK * DIM];   // 20480 B ; total 40960 -> 4 blocks = 160 KiB/CU
    const int tid = threadIdx.x;

    if (tid < DIM) {
        const int dm = tid;
        float v[NK], wid[NK], xpos[NK], hei[NK], ypos[NK], dv[NK + 1];
        float mx, sum, scale, c;

        mx = -1e30f;
        #pragma unroll
        for (int k = 0; k < NK; k++) { v[k] = wp[dm * NK + k]; mx = fmaxf(mx, v[k]); }
        sum = 0.f;
        #pragma unroll
        for (int k = 0; k < NK; k++) { v[k] = expf(v[k] - mx); sum += v[k]; }
        scale = 6.0f / sum;
        c = -BT;
        #pragma unroll
        for (int k = 0; k < NK; k++) { wid[k] = v[k] * scale; xpos[k] = c; c += wid[k]; }

        mx = -1e30f;
        #pragma unroll
        for (int k = 0; k < NK; k++) { v[k] = hp[dm * NK + k]; mx = fmaxf(mx, v[k]); }
        sum = 0.f;
        #pragma unroll
        for (int k = 0; k < NK; k++) { v[k] = expf(v[k] - mx); sum += v[k]; }
        scale = 6.0f / sum;
        c = -BT;
        #pragma unroll
        for (int k = 0; k < NK; k++) { hei[k] = v[k] * scale; ypos[k] = c; c += hei[k]; }

        dv[0] = 1.0f; dv[NK] = 1.0f;
        #pragma unroll
        for (int k = 0; k < 4; k++) dv[1 + k] = log1pf(expf(dp[dm * 4 + k]));

        #pragma unroll
        for (int k = 0; k < NK; k++) {
            float iw  = 1.0f / wid[k];
            float dlt = hei[k] * iw;
            float dk  = dv[k], dk1 = dv[k + 1];
            tabA[k * DIM + dm] = make_float4(xpos[k], iw, dk + dk1 - 2.0f * dlt, dlt);
            tabB[k * DIM + dm] = make_float4(hei[k] * (dlt - dk), hei[k] * dk,
                                             ypos[k], 2.0f * (dlt - dk));
        }
    }
    __syncthreads();

    const int lane = tid & 63;
    const int wv   = tid >> 6;

    // thread owns dims lane, lane+64, lane+128, lane+192; preload interior x-knots
    float kn[4][4];
    #pragma unroll
    for (int j = 0; j < 4; j++)
        #pragma unroll
        for (int i = 0; i < 4; i++)
            kn[j][i] = tabA[(i + 1) * DIM + lane + 64 * j].x;

    const int g = (blockIdx.x << 3) | wv;   // global wave id, 0..8191

    for (int it = 0; it < ITERS; it++) {
        const int r0 = (it << 14) | (g << 1);   // 16384 contiguous rows per sweep
        const float* up = u + (size_t)r0 * DIM + lane;

        float uin[2][4];
        #pragma unroll
        for (int rr = 0; rr < 2; rr++)
            #pragma unroll
            for (int j = 0; j < 4; j++)
                uin[rr][j] = up[rr * DIM + 64 * j];

        float lds[2] = {0.f, 0.f};
        #pragma unroll
        for (int rr = 0; rr < 2; rr++) {
            float xo[4];
            #pragma unroll
            for (int j = 0; j < 4; j++) {
                float uval = uin[rr][j];
                float uc = fminf(fmaxf(uval, -BT), BT);
                int idx = 0;
                idx += (uc >= kn[j][0]);
                idx += (uc >= kn[j][1]);
                idx += (uc >= kn[j][2]);
                idx += (uc >= kn[j][3]);
                const int off = idx * DIM + lane + 64 * j;
                float4 A  = tabA[off];
                float4 Bv = tabB[off];
                float xk = A.x, iw = A.y, s = A.z, dlt = A.w;
                float p = Bv.x, q = Bv.y, yk = Bv.z, rb = Bv.w;

                float th    = (uc - xk) * iw;
                float dk    = fmaf(-0.5f, rb, dlt);
                float r2    = dlt * dlt;
                float denom = fmaf(fmaf(-s, th, s), th, dlt);
                float invd  = __builtin_amdgcn_rcpf(denom);
                float num   = th * fmaf(p, th, q);
                float x_in  = fmaf(num, invd, yk);
                float ldq   = fmaf(fmaf(s, th, rb), th, dk);
                float ld    = __logf(ldq * r2 * invd * invd);

                xo[j] = (uc == uval) ? x_in : uval;
                lds[rr] += ld;           // == 0 (to fp eps) for tail elements
            }
            float* xp = x_out + (size_t)(r0 + rr) * DIM + lane;
            #pragma unroll
            for (int j = 0; j < 4; j++)
                __builtin_nontemporal_store(xo[j], xp + 64 * j);
        }

        #pragma unroll
        for (int off = 32; off > 0; off >>= 1) {
            lds[0] += __shfl_down(lds[0], off, 64);
            lds[1] += __shfl_down(lds[1], off, 64);
        }
        if (lane == 0) {
            __builtin_nontemporal_store(lds[0], ld_out + r0);
            __builtin_nontemporal_store(lds[1], ld_out + r0 + 1);
        }
    }
}

extern "C" void kernel_launch(void* const* d_in, const int* in_sizes, int n_in,
                              void* d_out, int out_size, void* d_ws, size_t ws_size,
                              hipStream_t stream) {
    const float* u  = (const float*)d_in[0];
    const float* w  = (const float*)d_in[1];
    const float* h  = (const float*)d_in[2];
    const float* dd = (const float*)d_in[3];
    float* x  = (float*)d_out;
    float* ld = x + (size_t)BATCH * DIM;
    rqs_kernel<<<NBLK, NTHR, 0, stream>>>(u, w, h, dd, x, ld);
}